// Round 8
// baseline (180.054 us; speedup 1.0000x reference)
//
#include <hip/hip_runtime.h>
#include <hip/hip_bf16.h>
#include <stdint.h>
#include <stddef.h>

#define M_DIM 8192
#define N_DIM 4096
#define K_DIM 4096
#define XSCALE 21.0f

typedef float f32x4 __attribute__((ext_vector_type(4)));
typedef int   i32x4 __attribute__((ext_vector_type(4)));
typedef char  i8x16 __attribute__((ext_vector_type(16)));

// merged conversion: x -> i8 (RNE, scale 21, clamp +-127), w -> sign i8
__global__ void __launch_bounds__(256) cvt_all_kernel(const float* __restrict__ x,
                                                      const float* __restrict__ w,
                                                      i8x16* __restrict__ xb,
                                                      i8x16* __restrict__ wb,
                                                      int n16x, int n16tot) {
    int i = blockIdx.x * 256 + threadIdx.x;
    const int stride = gridDim.x * 256;
    for (; i < n16tot; i += stride) {
        if (i < n16x) {
            const f32x4* p = reinterpret_cast<const f32x4*>(x) + (size_t)i * 4;
            i8x16 o;
            #pragma unroll
            for (int q = 0; q < 4; ++q) {
                f32x4 v = p[q];
                #pragma unroll
                for (int j = 0; j < 4; ++j) {
                    float t = fminf(127.f, fmaxf(-127.f, v[j] * XSCALE));
                    o[q * 4 + j] = (char)__float2int_rn(t);
                }
            }
            xb[i] = o;
        } else {
            int jj = i - n16x;
            const f32x4* p = reinterpret_cast<const f32x4*>(w) + (size_t)jj * 4;
            i8x16 o;
            #pragma unroll
            for (int q = 0; q < 4; ++q) {
                f32x4 v = p[q];
                #pragma unroll
                for (int j = 0; j < 4; ++j)
                    o[q * 4 + j] = (char)((v[j] > 0.f) - (v[j] < 0.f));
            }
            wb[jj] = o;
        }
    }
}

// ---------------------------------------------------------------------------
// 256x256 8-phase i8 GEMM, round 8: fragment READ-AHEAD on the round-7
// skeleton. Staging order and WVM(4)@ph3/ph7 placement preserved EXACTLY
// (proven 0-stall: every vmcnt guards >=2-phase-old loads). Phase p issues
// the ds_reads for phase p+1's MFMA before BAR1, then MFMA(p) runs on frags
// read last phase -- reads drain under the barrier-wait + MFMA shadow,
// overlapping the ~2048 cyc/K-tile LDS window with the ~2611 cyc MFMA window.
// Cross-buffer reads sit at ph3/ph7 AFTER the WVM(4) that certifies the
// buffer they read. WAR: each phase's WLG0 retires its reads >=3 barriers
// before any DMA overwrites that region. Frag sets: a0F,a1F (8 frags ea),
// b0F,b1F,b0nF (4 frags ea) -- round-5-proven register layout.
// ---------------------------------------------------------------------------

#define BAR() do { asm volatile("" ::: "memory"); __builtin_amdgcn_s_barrier(); asm volatile("" ::: "memory"); } while (0)
#define WLG0() asm volatile("s_waitcnt lgkmcnt(0)" ::: "memory")
#define WVM(n) asm volatile("s_waitcnt vmcnt(" #n ")" ::: "memory")

#define STAGE_A(d, kt, h) do { \
    const char* _g = aSrc + (size_t)((h) * 128) * K_DIM + (size_t)(kt) * 128; \
    __builtin_amdgcn_global_load_lds((const __attribute__((address_space(1))) void*)_g, \
        (__attribute__((address_space(3))) void*)(smem + (d) * 65536 + (h) * 16384 + wave * 1024), 16, 0, 0); \
    __builtin_amdgcn_global_load_lds((const __attribute__((address_space(1))) void*)(_g + (size_t)64 * K_DIM), \
        (__attribute__((address_space(3))) void*)(smem + (d) * 65536 + (h) * 16384 + 8192 + wave * 1024), 16, 0, 0); \
} while (0)

#define STAGE_B(d, kt, h) do { \
    const char* _g = bSrc + (size_t)((h) * 128) * K_DIM + (size_t)(kt) * 128; \
    __builtin_amdgcn_global_load_lds((const __attribute__((address_space(1))) void*)_g, \
        (__attribute__((address_space(3))) void*)(smem + (d) * 65536 + 32768 + (h) * 16384 + wave * 1024), 16, 0, 0); \
    __builtin_amdgcn_global_load_lds((const __attribute__((address_space(1))) void*)(_g + (size_t)64 * K_DIM), \
        (__attribute__((address_space(3))) void*)(smem + (d) * 65536 + 32768 + (h) * 16384 + 8192 + wave * 1024), 16, 0, 0); \
} while (0)

// read one A quad (qm half) into dst[mi][ks]: 8 x ds_read_b128
#define RD_A(dst, sAc, qm) do { \
    _Pragma("unroll") \
    for (int _mi = 0; _mi < 4; ++_mi) { \
        dst[_mi][0] = *(const i32x4*)((sAc) + aRowB + (qm) * 8192 + _mi * 2048 + kx0); \
        dst[_mi][1] = *(const i32x4*)((sAc) + aRowB + (qm) * 8192 + _mi * 2048 + kx1); \
    } \
} while (0)

// read one B quad (qn half) into dst[ni][ks]: 4 x ds_read_b128
#define RD_B(dst, sBc, qn) do { \
    _Pragma("unroll") \
    for (int _ni = 0; _ni < 2; ++_ni) { \
        dst[_ni][0] = *(const i32x4*)((sBc) + bRowB + (qn) * 4096 + _ni * 2048 + kx0); \
        dst[_ni][1] = *(const i32x4*)((sBc) + bRowB + (qn) * 4096 + _ni * 2048 + kx1); \
    } \
} while (0)

// 16 MFMAs: quad (qm,qn) of the C tile from frag sets aS/bS
#define MQ(aS, bS, qm, qn) do { \
    __builtin_amdgcn_s_setprio(1); \
    _Pragma("unroll") \
    for (int _mi = 0; _mi < 4; ++_mi) \
    _Pragma("unroll") \
    for (int _ni = 0; _ni < 2; ++_ni) \
    _Pragma("unroll") \
    for (int _ks = 0; _ks < 2; ++_ks) \
        acc[(qm) * 4 + _mi][(qn) * 2 + _ni] = __builtin_amdgcn_mfma_i32_16x16x64_i8( \
            aS[_mi][_ks], bS[_ni][_ks], acc[(qm) * 4 + _mi][(qn) * 2 + _ni], 0, 0, 0); \
    __builtin_amdgcn_s_setprio(0); \
} while (0)

__global__ void __launch_bounds__(512, 2) gemm_bin_256(
        const char* __restrict__ A,   // [M][K] i8 (x * 21, RNE)
        const char* __restrict__ B,   // [N][K] i8 sign weights
        const float* __restrict__ bias,
        float* __restrict__ C) {
    __shared__ __align__(16) char smem[131072];

    const int tid  = threadIdx.x;
    const int lane = tid & 63;
    const int wave = tid >> 6;
    const int wm = wave >> 2;      // 0..1
    const int wn = wave & 3;       // 0..3

    // XCD-bijective swizzle: nwg=512, 512/8=64 per XCD
    const int wgid = (blockIdx.x & 7) * 64 + (blockIdx.x >> 3);
    const int m0 = (wgid >> 4) * 256;   // 32 m-tiles
    const int n0 = (wgid & 15) * 256;   // 16 n-tiles

    // staging: thread t writes LDS linear t*16B => row t/8, phys 16B-blk t%8;
    // source carries the inverse swizzle
    const int srow = tid >> 3;          // 0..63
    const int scolblk = (tid & 7) ^ (srow & 7);
    const char* aSrc = A + (size_t)(m0 + srow) * K_DIM + scolblk * 16;
    const char* bSrc = B + (size_t)(n0 + srow) * K_DIM + scolblk * 16;

    // ds_read addressing: logical blk = ks*4 + (lane>>4), phys = logical ^ (row&7)
    const int aRowB = (wm * 128 + (lane & 15)) * 128;
    const int bRowB = (wn * 64 + (lane & 15)) * 128;
    const int kx0 = ((lane >> 4) ^ (lane & 7)) * 16;
    const int kx1 = kx0 ^ 64;

    const char* sA0 = smem;
    const char* sB0 = smem + 32768;
    const char* sA1 = smem + 65536;
    const char* sB1 = smem + 98304;

    i32x4 a0F[4][2], a1F[4][2];
    i32x4 b0F[2][2], b1F[2][2], b0nF[2][2];
    i32x4 acc[8][4];
    #pragma unroll
    for (int i = 0; i < 8; ++i)
        #pragma unroll
        for (int j = 0; j < 4; ++j)
            acc[i][j] = i32x4{0, 0, 0, 0};

    // prologue: tile0 -> buf0 landed; issue B(1); preload quad-0 frags
    STAGE_B(0, 0, 0); STAGE_B(0, 0, 1);
    STAGE_A(0, 0, 0); STAGE_A(0, 0, 1);
    WVM(0); BAR();
    STAGE_B(1, 1, 0); STAGE_B(1, 1, 1);
    RD_B(b0F, sB0, 0); RD_A(a0F, sA0, 0);

    for (int it = 0; it < 15; ++it) {
        const int k1 = 2 * it + 1, k2 = 2 * it + 2, k3 = 2 * it + 3;
        // ph0: MFMA (0,0)@buf0; read B-q1 for ph1
        RD_B(b1F, sB0, 1); STAGE_A(1, k1, 0);
        BAR(); MQ(a0F, b0F, 0, 0); WLG0(); BAR();
        // ph1: MFMA (0,1)@buf0; read A-q1 for ph2
        RD_A(a1F, sA0, 1); STAGE_A(1, k1, 1);
        BAR(); MQ(a0F, b1F, 0, 1); WLG0(); BAR();
        // ph2: MFMA (1,1)@buf0 (no reads this phase)
        STAGE_B(0, k2, 0);
        BAR(); MQ(a1F, b1F, 1, 1); BAR();
        // ph3: WVM(4) certifies buf1 (A k1 @ph0/1, B k1 @prev ph6/7);
        //      read buf1 quad-0 for ph4; MFMA (1,0)@buf0
        STAGE_B(0, k2, 1); WVM(4);
        RD_B(b0nF, sB1, 0); RD_A(a0F, sA1, 0);
        BAR(); MQ(a1F, b0F, 1, 0); WLG0(); BAR();
        // ph4: MFMA (0,0)@buf1; read B-q1 for ph5
        RD_B(b1F, sB1, 1); STAGE_A(0, k2, 0);
        BAR(); MQ(a0F, b0nF, 0, 0); WLG0(); BAR();
        // ph5: MFMA (0,1)@buf1; read A-q1 for ph6
        RD_A(a1F, sA1, 1); STAGE_A(0, k2, 1);
        BAR(); MQ(a0F, b1F, 0, 1); WLG0(); BAR();
        // ph6: MFMA (1,1)@buf1 (no reads)
        STAGE_B(1, k3, 0);
        BAR(); MQ(a1F, b1F, 1, 1); BAR();
        // ph7: WVM(4) certifies buf0 (B k2 @ph2/3, A k2 @ph4/5);
        //      read buf0 quad-0 for next ph0; MFMA (1,0)@buf1
        STAGE_B(1, k3, 1); WVM(4);
        RD_B(b0F, sB0, 0); RD_A(a0F, sA0, 0);
        BAR(); MQ(a1F, b0nF, 1, 0); WLG0(); BAR();
    }

    // tail: tiles 30 (buf0), 31 (buf1); stage only A(31)
    RD_B(b1F, sB0, 1); STAGE_A(1, 31, 0);
    BAR(); MQ(a0F, b0F, 0, 0); WLG0(); BAR();
    RD_A(a1F, sA0, 1); STAGE_A(1, 31, 1);
    BAR(); MQ(a0F, b1F, 0, 1); WLG0(); BAR();
    BAR(); MQ(a1F, b1F, 1, 1); BAR();
    WVM(0);
    RD_B(b0nF, sB1, 0); RD_A(a0F, sA1, 0);
    BAR(); MQ(a1F, b0F, 1, 0); WLG0(); BAR();
    RD_B(b1F, sB1, 1);
    BAR(); MQ(a0F, b0nF, 0, 0); WLG0(); BAR();
    RD_A(a1F, sA1, 1);
    BAR(); MQ(a0F, b1F, 0, 1); WLG0(); BAR();
    BAR(); MQ(a1F, b1F, 1, 1); BAR();
    MQ(a1F, b0nF, 1, 0);

    // epilogue: C/D layout col = lane&15, row = (lane>>4)*4 + j
    const float inv_s = 1.0f / XSCALE;
    const int erow0 = m0 + wm * 128 + ((lane >> 4) << 2);
    const int ecol0 = n0 + wn * 64 + (lane & 15);
    float bv[4];
    #pragma unroll
    for (int ng = 0; ng < 4; ++ng) bv[ng] = bias[ecol0 + ng * 16];
    #pragma unroll
    for (int ag = 0; ag < 8; ++ag)
        #pragma unroll
        for (int ng = 0; ng < 4; ++ng)
            #pragma unroll
            for (int j = 0; j < 4; ++j)
                C[(size_t)(erow0 + ag * 16 + j) * N_DIM + ecol0 + ng * 16] =
                    (float)acc[ag][ng][j] * inv_s + bv[ng];
}

// ---- correctness fallback if workspace is too small (not expected) ----
__global__ void __launch_bounds__(256) fallback_kernel(const float* __restrict__ x,
        const float* __restrict__ w, const float* __restrict__ bias,
        float* __restrict__ out) {
    const size_t idx = (size_t)blockIdx.x * 256 + threadIdx.x;
    const int m = (int)(idx / N_DIM);
    const int n = (int)(idx % N_DIM);
    const float* xr = x + (size_t)m * K_DIM;
    const float* wr = w + (size_t)n * K_DIM;
    float s = 0.f;
    for (int k = 0; k < K_DIM; k += 4) {
        f32x4 a = *reinterpret_cast<const f32x4*>(xr + k);
        f32x4 b = *reinterpret_cast<const f32x4*>(wr + k);
        #pragma unroll
        for (int j = 0; j < 4; ++j)
            s += (b[j] > 0.f) ? a[j] : ((b[j] < 0.f) ? -a[j] : 0.f);
    }
    out[idx] = s + bias[n];
}

extern "C" void kernel_launch(void* const* d_in, const int* in_sizes, int n_in,
                              void* d_out, int out_size, void* d_ws, size_t ws_size,
                              hipStream_t stream) {
    const float* x    = (const float*)d_in[0];
    const float* w    = (const float*)d_in[1];
    const float* bias = (const float*)d_in[2];
    float* out = (float*)d_out;

    const size_t a_bytes = (size_t)M_DIM * K_DIM;   // 33.6 MB i8
    const size_t w_bytes = (size_t)N_DIM * K_DIM;   // 16.8 MB i8

    if (ws_size >= a_bytes + w_bytes) {
        char* xb = (char*)d_ws;
        char* wb = (char*)d_ws + a_bytes;

        const int n16x = (M_DIM * K_DIM) / 16;
        const int n16w = (N_DIM * K_DIM) / 16;
        cvt_all_kernel<<<2048, 256, 0, stream>>>(x, w, (i8x16*)xb, (i8x16*)wb,
                                                 n16x, n16x + n16w);

        gemm_bin_256<<<512, 512, 0, stream>>>(xb, wb, bias, out);
    } else {
        fallback_kernel<<<(M_DIM * (N_DIM / 256)), 256, 0, stream>>>(x, w, bias, out);
    }
}

// Round 9
// 169.106 us; speedup vs baseline: 1.0647x; 1.0647x over previous
//
#include <hip/hip_runtime.h>
#include <hip/hip_bf16.h>
#include <stdint.h>
#include <stddef.h>

#define M_DIM 8192
#define N_DIM 4096
#define K_DIM 4096
#define XSCALE 21.0f

typedef float f32x4 __attribute__((ext_vector_type(4)));
typedef int   i32x4 __attribute__((ext_vector_type(4)));
typedef char  i8x16 __attribute__((ext_vector_type(16)));

// merged conversion: x -> i8 (RNE, scale 21, clamp +-127), w -> sign i8
__global__ void __launch_bounds__(256) cvt_all_kernel(const float* __restrict__ x,
                                                      const float* __restrict__ w,
                                                      i8x16* __restrict__ xb,
                                                      i8x16* __restrict__ wb,
                                                      int n16x, int n16tot) {
    int i = blockIdx.x * 256 + threadIdx.x;
    const int stride = gridDim.x * 256;
    for (; i < n16tot; i += stride) {
        if (i < n16x) {
            const f32x4* p = reinterpret_cast<const f32x4*>(x) + (size_t)i * 4;
            i8x16 o;
            #pragma unroll
            for (int q = 0; q < 4; ++q) {
                f32x4 v = p[q];
                #pragma unroll
                for (int j = 0; j < 4; ++j) {
                    float t = fminf(127.f, fmaxf(-127.f, v[j] * XSCALE));
                    o[q * 4 + j] = (char)__float2int_rn(t);
                }
            }
            xb[i] = o;
        } else {
            int jj = i - n16x;
            const f32x4* p = reinterpret_cast<const f32x4*>(w) + (size_t)jj * 4;
            i8x16 o;
            #pragma unroll
            for (int q = 0; q < 4; ++q) {
                f32x4 v = p[q];
                #pragma unroll
                for (int j = 0; j < 4; ++j)
                    o[q * 4 + j] = (char)((v[j] > 0.f) - (v[j] < 0.f));
            }
            wb[jj] = o;
        }
    }
}

// ---------------------------------------------------------------------------
// 256x256 i8 GEMM, round 9: MEGA-PHASE. One phase and ONE barrier per K-tile
// (BK=128): stage next tile (8 gload_lds) -> all 24 ds_reads -> all 64 MFMAs
// (dependency-driven partial lgkm waits: first MFMA quad starts after 12
// reads) -> WLG0 + WVM(0) -> BAR. With a ~2800-cyc barrier interval, the 8
// waves de-synchronize and one wave's LDS reads overlap another's MFMAs
// (m114 self-organizing overlap) -- the fine-phase lockstep that pinned
// rounds 2-8 at ~47-52% MfmaUtil is removed. Hazards at 1 barrier/K-tile:
// WLG0 retires reads(c) before next iter's DMA overwrites c; WVM(0) (free:
// stage issued ~1900 cyc earlier) certifies c^1 before its reads after BAR.
// Geometry, swizzle, staging map, frag addressing: round-7 verbatim.
// ---------------------------------------------------------------------------

#define BAR() do { asm volatile("" ::: "memory"); __builtin_amdgcn_s_barrier(); asm volatile("" ::: "memory"); } while (0)
#define WLG0() asm volatile("s_waitcnt lgkmcnt(0)" ::: "memory")
#define WVM(n) asm volatile("s_waitcnt vmcnt(" #n ")" ::: "memory")

#define STAGE_A(d, kt, h) do { \
    const char* _g = aSrc + (size_t)((h) * 128) * K_DIM + (size_t)(kt) * 128; \
    __builtin_amdgcn_global_load_lds((const __attribute__((address_space(1))) void*)_g, \
        (__attribute__((address_space(3))) void*)(smem + (d) * 65536 + (h) * 16384 + wave * 1024), 16, 0, 0); \
    __builtin_amdgcn_global_load_lds((const __attribute__((address_space(1))) void*)(_g + (size_t)64 * K_DIM), \
        (__attribute__((address_space(3))) void*)(smem + (d) * 65536 + (h) * 16384 + 8192 + wave * 1024), 16, 0, 0); \
} while (0)

#define STAGE_B(d, kt, h) do { \
    const char* _g = bSrc + (size_t)((h) * 128) * K_DIM + (size_t)(kt) * 128; \
    __builtin_amdgcn_global_load_lds((const __attribute__((address_space(1))) void*)_g, \
        (__attribute__((address_space(3))) void*)(smem + (d) * 65536 + 32768 + (h) * 16384 + wave * 1024), 16, 0, 0); \
    __builtin_amdgcn_global_load_lds((const __attribute__((address_space(1))) void*)(_g + (size_t)64 * K_DIM), \
        (__attribute__((address_space(3))) void*)(smem + (d) * 65536 + 32768 + (h) * 16384 + 8192 + wave * 1024), 16, 0, 0); \
} while (0)

// read one A quad (qm half) into dst[mi][ks]: 8 x ds_read_b128
#define RD_A(dst, sAc, qm) do { \
    _Pragma("unroll") \
    for (int _mi = 0; _mi < 4; ++_mi) { \
        dst[_mi][0] = *(const i32x4*)((sAc) + aRowB + (qm) * 8192 + _mi * 2048 + kx0); \
        dst[_mi][1] = *(const i32x4*)((sAc) + aRowB + (qm) * 8192 + _mi * 2048 + kx1); \
    } \
} while (0)

// read one B quad (qn half) into dst[ni][ks]: 4 x ds_read_b128
#define RD_B(dst, sBc, qn) do { \
    _Pragma("unroll") \
    for (int _ni = 0; _ni < 2; ++_ni) { \
        dst[_ni][0] = *(const i32x4*)((sBc) + bRowB + (qn) * 4096 + _ni * 2048 + kx0); \
        dst[_ni][1] = *(const i32x4*)((sBc) + bRowB + (qn) * 4096 + _ni * 2048 + kx1); \
    } \
} while (0)

// 16 MFMAs: quad (qm,qn) of the C tile from frag sets aS/bS
#define MQ(aS, bS, qm, qn) do { \
    __builtin_amdgcn_s_setprio(1); \
    _Pragma("unroll") \
    for (int _mi = 0; _mi < 4; ++_mi) \
    _Pragma("unroll") \
    for (int _ni = 0; _ni < 2; ++_ni) \
    _Pragma("unroll") \
    for (int _ks = 0; _ks < 2; ++_ks) \
        acc[(qm) * 4 + _mi][(qn) * 2 + _ni] = __builtin_amdgcn_mfma_i32_16x16x64_i8( \
            aS[_mi][_ks], bS[_ni][_ks], acc[(qm) * 4 + _mi][(qn) * 2 + _ni], 0, 0, 0); \
    __builtin_amdgcn_s_setprio(0); \
} while (0)

// one K-tile: optional stage of tile kt_s into buf ds, full compute on (sAc,sBc)
#define KTILE_STAGE(sAc, sBc, ds, kt_s) do { \
    STAGE_A(ds, kt_s, 0); STAGE_A(ds, kt_s, 1); \
    STAGE_B(ds, kt_s, 0); STAGE_B(ds, kt_s, 1); \
    RD_B(b0F, sBc, 0); RD_A(a0F, sAc, 0); \
    RD_B(b1F, sBc, 1); RD_A(a1F, sAc, 1); \
    MQ(a0F, b0F, 0, 0); MQ(a0F, b1F, 0, 1); \
    MQ(a1F, b1F, 1, 1); MQ(a1F, b0F, 1, 0); \
    WLG0(); WVM(0); BAR(); \
} while (0)

__global__ void __launch_bounds__(512, 2) gemm_bin_256(
        const char* __restrict__ A,   // [M][K] i8 (x * 21, RNE)
        const char* __restrict__ B,   // [N][K] i8 sign weights
        const float* __restrict__ bias,
        float* __restrict__ C) {
    __shared__ __align__(16) char smem[131072];

    const int tid  = threadIdx.x;
    const int lane = tid & 63;
    const int wave = tid >> 6;
    const int wm = wave >> 2;      // 0..1
    const int wn = wave & 3;       // 0..3

    // XCD-bijective swizzle: nwg=512, 512/8=64 per XCD
    const int wgid = (blockIdx.x & 7) * 64 + (blockIdx.x >> 3);
    const int m0 = (wgid >> 4) * 256;   // 32 m-tiles
    const int n0 = (wgid & 15) * 256;   // 16 n-tiles

    // staging: thread t writes LDS linear t*16B => row t/8, phys 16B-blk t%8;
    // source carries the inverse swizzle
    const int srow = tid >> 3;          // 0..63
    const int scolblk = (tid & 7) ^ (srow & 7);
    const char* aSrc = A + (size_t)(m0 + srow) * K_DIM + scolblk * 16;
    const char* bSrc = B + (size_t)(n0 + srow) * K_DIM + scolblk * 16;

    // ds_read addressing: logical blk = ks*4 + (lane>>4), phys = logical ^ (row&7)
    const int aRowB = (wm * 128 + (lane & 15)) * 128;
    const int bRowB = (wn * 64 + (lane & 15)) * 128;
    const int kx0 = ((lane >> 4) ^ (lane & 7)) * 16;
    const int kx1 = kx0 ^ 64;

    const char* sA0 = smem;
    const char* sB0 = smem + 32768;
    const char* sA1 = smem + 65536;
    const char* sB1 = smem + 98304;

    i32x4 a0F[4][2], a1F[4][2];
    i32x4 b0F[2][2], b1F[2][2];
    i32x4 acc[8][4];
    #pragma unroll
    for (int i = 0; i < 8; ++i)
        #pragma unroll
        for (int j = 0; j < 4; ++j)
            acc[i][j] = i32x4{0, 0, 0, 0};

    // prologue: tile0 -> buf0, landed
    STAGE_A(0, 0, 0); STAGE_A(0, 0, 1);
    STAGE_B(0, 0, 0); STAGE_B(0, 0, 1);
    WVM(0); BAR();

    // main: tiles 0..29 (unroll x2 for static buffer selection)
    for (int it = 0; it < 15; ++it) {
        KTILE_STAGE(sA0, sB0, 1, 2 * it + 1);   // tile 2it   (buf0), stage -> buf1
        KTILE_STAGE(sA1, sB1, 0, 2 * it + 2);   // tile 2it+1 (buf1), stage -> buf0
    }
    // tile 30 (buf0), stage 31 -> buf1
    KTILE_STAGE(sA0, sB0, 1, 31);
    // tile 31 (buf1), no stage, no trailing barrier needed
    RD_B(b0F, sB1, 0); RD_A(a0F, sA1, 0);
    RD_B(b1F, sB1, 1); RD_A(a1F, sA1, 1);
    MQ(a0F, b0F, 0, 0); MQ(a0F, b1F, 0, 1);
    MQ(a1F, b1F, 1, 1); MQ(a1F, b0F, 1, 0);

    // epilogue: C/D layout col = lane&15, row = (lane>>4)*4 + j
    const float inv_s = 1.0f / XSCALE;
    const int erow0 = m0 + wm * 128 + ((lane >> 4) << 2);
    const int ecol0 = n0 + wn * 64 + (lane & 15);
    float bv[4];
    #pragma unroll
    for (int ng = 0; ng < 4; ++ng) bv[ng] = bias[ecol0 + ng * 16];
    #pragma unroll
    for (int ag = 0; ag < 8; ++ag)
        #pragma unroll
        for (int ng = 0; ng < 4; ++ng)
            #pragma unroll
            for (int j = 0; j < 4; ++j)
                C[(size_t)(erow0 + ag * 16 + j) * N_DIM + ecol0 + ng * 16] =
                    (float)acc[ag][ng][j] * inv_s + bv[ng];
}

// ---- correctness fallback if workspace is too small (not expected) ----
__global__ void __launch_bounds__(256) fallback_kernel(const float* __restrict__ x,
        const float* __restrict__ w, const float* __restrict__ bias,
        float* __restrict__ out) {
    const size_t idx = (size_t)blockIdx.x * 256 + threadIdx.x;
    const int m = (int)(idx / N_DIM);
    const int n = (int)(idx % N_DIM);
    const float* xr = x + (size_t)m * K_DIM;
    const float* wr = w + (size_t)n * K_DIM;
    float s = 0.f;
    for (int k = 0; k < K_DIM; k += 4) {
        f32x4 a = *reinterpret_cast<const f32x4*>(xr + k);
        f32x4 b = *reinterpret_cast<const f32x4*>(wr + k);
        #pragma unroll
        for (int j = 0; j < 4; ++j)
            s += (b[j] > 0.f) ? a[j] : ((b[j] < 0.f) ? -a[j] : 0.f);
    }
    out[idx] = s + bias[n];
}

extern "C" void kernel_launch(void* const* d_in, const int* in_sizes, int n_in,
                              void* d_out, int out_size, void* d_ws, size_t ws_size,
                              hipStream_t stream) {
    const float* x    = (const float*)d_in[0];
    const float* w    = (const float*)d_in[1];
    const float* bias = (const float*)d_in[2];
    float* out = (float*)d_out;

    const size_t a_bytes = (size_t)M_DIM * K_DIM;   // 33.6 MB i8
    const size_t w_bytes = (size_t)N_DIM * K_DIM;   // 16.8 MB i8

    if (ws_size >= a_bytes + w_bytes) {
        char* xb = (char*)d_ws;
        char* wb = (char*)d_ws + a_bytes;

        const int n16x = (M_DIM * K_DIM) / 16;
        const int n16w = (N_DIM * K_DIM) / 16;
        cvt_all_kernel<<<2048, 256, 0, stream>>>(x, w, (i8x16*)xb, (i8x16*)wb,
                                                 n16x, n16x + n16w);

        gemm_bin_256<<<512, 512, 0, stream>>>(xb, wb, bias, out);
    } else {
        fallback_kernel<<<(M_DIM * (N_DIM / 256)), 256, 0, stream>>>(x, w, bias, out);
    }
}